// Round 9
// baseline (816.759 us; speedup 1.0000x reference)
//
#include <hip/hip_runtime.h>
#include <math.h>

#define NB 64       // batch
#define NS 512      // seq len
#define ND 512      // input dim
#define NH 512      // hidden
#define NC (NS / 8) // chunks of 8 steps
#define NE 2        // batch elements per block pair

__device__ __forceinline__ float dot8(float4 a0, float4 a1, float4 x0, float4 x1) {
    float s = a0.x * x0.x;
    s = fmaf(a0.y, x0.y, s); s = fmaf(a0.z, x0.z, s); s = fmaf(a0.w, x0.w, s);
    s = fmaf(a1.x, x1.x, s); s = fmaf(a1.y, x1.y, s); s = fmaf(a1.z, x1.z, s);
    s = fmaf(a1.w, x1.w, s);
    return s;
}

// 64-lane sum via DPP (VALU only, no LDS). Total ends in lane 63.
__device__ __forceinline__ float dpp_sum64(float x) {
    x += __int_as_float(__builtin_amdgcn_update_dpp(0, __float_as_int(x), 0x111, 0xf, 0xf, true)); // row_shr:1
    x += __int_as_float(__builtin_amdgcn_update_dpp(0, __float_as_int(x), 0x112, 0xf, 0xf, true)); // row_shr:2
    x += __int_as_float(__builtin_amdgcn_update_dpp(0, __float_as_int(x), 0x114, 0xf, 0xf, true)); // row_shr:4
    x += __int_as_float(__builtin_amdgcn_update_dpp(0, __float_as_int(x), 0x118, 0xf, 0xf, true)); // row_shr:8
    x += __int_as_float(__builtin_amdgcn_update_dpp(0, __float_as_int(x), 0x142, 0xa, 0xf, true)); // row_bcast:15
    x += __int_as_float(__builtin_amdgcn_update_dpp(0, __float_as_int(x), 0x143, 0xc, 0xf, true)); // row_bcast:31
    return x;
}

__device__ __forceinline__ float bcast63(float x) {
    return __int_as_float(__builtin_amdgcn_readlane(__float_as_int(x), 63));
}

__device__ __forceinline__ float sigm(float x) {
    return 1.0f / (1.0f + __expf(-x));
}

__device__ __forceinline__ float tanh_fast(float x) {
    float ax = fabsf(x);
    float e = __expf(2.0f * ax);
    float r = 1.0f - 2.0f / (e + 1.0f);
    return copysignf(r, x);
}

// lgkm-only barrier: global stores stay in flight across steps.
__device__ __forceinline__ void wg_barrier() {
    asm volatile("s_waitcnt lgkmcnt(0)\n\ts_barrier" ::: "memory");
}
// full-drain barrier: all waves' VMEM ops retired before anyone passes.
__device__ __forceinline__ void full_barrier() {
    asm volatile("s_waitcnt vmcnt(0) lgkmcnt(0)\n\ts_barrier" ::: "memory");
}

// permuted weight gather for the hs slot layout (slot s = row 8*(s&63)+(s>>6))
#define LOADWP(mat, ra, rb)                                                   \
    {                                                                         \
        const float* M = (mat) + wv * NH;                                     \
        ra = make_float4(M[kb], M[kb + 8], M[kb + 16], M[kb + 24]);           \
        rb = make_float4(M[kb + 4], M[kb + 12], M[kb + 20], M[kb + 28]);      \
    }

// ---------------------------------------------------------------------------
// Kernel A: chunk-major P table:
// PT[((b*NC + t/8)*8 + f)*16 + (t%8)*2 + {0,1}] = {(W12@x)[f], (dW12@x)[f]}
// ---------------------------------------------------------------------------
__global__ __launch_bounds__(64) void precomp_kernel(
    const float* __restrict__ x, const float* __restrict__ W12,
    const float* __restrict__ dW12, float* __restrict__ PT) {
    int bt = blockIdx.x;
    int b = bt >> 9, t = bt & (NS - 1);
    int l = threadIdx.x;  // 0..63
    const float4* xr = (const float4*)(x + (size_t)bt * ND);
    float4 xv0 = xr[l];
    float4 xv1 = xr[64 + l];

    float acc[16];
#pragma unroll
    for (int f = 0; f < 8; ++f) {
        const float4* w = (const float4*)(W12 + f * ND);
        acc[f] = dot8(w[l], w[64 + l], xv0, xv1);
        const float4* dw = (const float4*)(dW12 + f * ND);
        acc[8 + f] = dot8(dw[l], dw[64 + l], xv0, xv1);
    }
#pragma unroll
    for (int f = 0; f < 16; ++f) acc[f] = dpp_sum64(acc[f]);

    if (l == 63) {
        float* base = PT + (((size_t)b * NC + (t >> 3)) * 8) * 16 + (t & 7) * 2;
#pragma unroll
        for (int f = 0; f < 8; ++f)
            *(float2*)&base[f * 16] = make_float2(acc[f], acc[8 + f]);
    }
}

// ---------------------------------------------------------------------------
// Kernel B: 2-stage pipeline, NE=2 batch elements per block.
// grid = 2 * (NB/NE) = 64 blocks of 512.
// role 0 (bid<32):  layer-1 recurrence for elems {2p,2p+1} + W22/dW22
//                   projections -> mvalT chunk records + flags.
// role 1 (bid>=32): layer-2 recurrence for the same pair, chunk-batched
//                   m-loads, permuted LDS, scattered fire-forget out stores.
// Weights/coefs are batch-invariant -> shared across both elements.
// ---------------------------------------------------------------------------
__global__ __launch_bounds__(512, 2) void lstm_pipe_kernel(
    const float* __restrict__ PT, const float* __restrict__ h0,
    const float* __restrict__ c0,
    const float* __restrict__ W11, const float* __restrict__ U11,
    const float* __restrict__ dW11, const float* __restrict__ dU11,
    const float* __restrict__ U12, const float* __restrict__ dU12,
    const float* __restrict__ b11, const float* __restrict__ b12,
    const float* __restrict__ W21, const float* __restrict__ U21,
    const float* __restrict__ dW21, const float* __restrict__ dU21,
    const float* __restrict__ W22, const float* __restrict__ dW22,
    const float* __restrict__ U22, const float* __restrict__ dU22,
    const float* __restrict__ b21, const float* __restrict__ b22,
    float* __restrict__ mvalT, unsigned int* __restrict__ flagb,
    float* __restrict__ out) {
    int role = blockIdx.x >> 5;
    int pr = blockIdx.x & 31;
    int tid = threadIdx.x;
    int wv = tid >> 6;            // wave = factor row
    int l = tid & 63;             // lane
    int h = 8 * l + wv;           // owned hidden row
    int kb = 32 * (l & 15) + (l >> 4);

    __shared__ float hs[2][NE][NH];   // 8 KB, permuted: slot tid = own row

    float* hn = out + (size_t)NB * NS * NH;
    float* cn = hn + (size_t)2 * NB * NH;

    if (role == 0) {
        // =================== PRODUCER: layer 1 (x NE) ===================
        float4 u12a, u12b, du12a, du12b, w22a, w22b, dw22a, dw22b;
        LOADWP(U12, u12a, u12b)
        LOADWP(dU12, du12a, du12b)
        LOADWP(W22, w22a, w22b)
        LOADWP(dW22, dw22a, dw22b)
        float cW1[4], cdW1[4], cU1[4], cdU1[4], bb1[4];
#pragma unroll
        for (int q = 0; q < 4; ++q) {
            int idx = q * 64 + l;
            cW1[q] = W11[idx]; cdW1[q] = dW11[idx];
            cU1[q] = U11[idx]; cdU1[q] = dU11[idx];
            bb1[q] = b11[q * NH + h] + b12[q * NH + h];
        }
        float c1[NE], h1v[NE];
#pragma unroll
        for (int e = 0; e < NE; ++e) {
            int eb = pr * NE + e;
            c1[e] = c0[(size_t)eb * NH + h];
            h1v[e] = h0[(size_t)eb * NH + h];
            hs[0][e][tid] = h1v[e];
        }
        // chunk-0 P records -> registers (unpacked)
        float pa1[NE][8], pa2[NE][8];
#pragma unroll
        for (int e = 0; e < NE; ++e) {
            int eb = pr * NE + e;
            const float4* rp = (const float4*)(PT + (((size_t)eb * NC) * 8 + wv) * 16);
#pragma unroll
            for (int k = 0; k < 4; ++k) {
                float4 v = rp[k];
                pa1[e][2 * k] = v.x;     pa2[e][2 * k] = v.y;
                pa1[e][2 * k + 1] = v.z; pa2[e][2 * k + 1] = v.w;
            }
        }
        wg_barrier();

        // ---- prologue: h1(1) for both elems ----
        {
            float m3[NE], m4[NE];
#pragma unroll
            for (int e = 0; e < NE; ++e) {
                float4 x0 = *(const float4*)&hs[0][e][4 * l];
                float4 x1 = *(const float4*)&hs[0][e][256 + 4 * l];
                float r3 = dot8(u12a, u12b, x0, x1);
                float r4 = dot8(du12a, du12b, x0, x1);
                m3[e] = bcast63(dpp_sum64(r3));
                m4[e] = bcast63(dpp_sum64(r4));
            }
            wg_barrier();  // WAR on hs[0]
#pragma unroll
            for (int e = 0; e < NE; ++e) {
                float px = pa1[e][0], py = pa2[e][0];
                float g0 = cW1[0] * px + cdW1[0] * py + cU1[0] * m3[e] + cdU1[0] * m4[e] + bb1[0];
                float g1 = cW1[1] * px + cdW1[1] * py + cU1[1] * m3[e] + cdU1[1] * m4[e] + bb1[1];
                float g2 = cW1[2] * px + cdW1[2] * py + cU1[2] * m3[e] + cdU1[2] * m4[e] + bb1[2];
                float g3 = cW1[3] * px + cdW1[3] * py + cU1[3] * m3[e] + cdU1[3] * m4[e] + bb1[3];
                float ig = sigm(g0), fg = sigm(g1), gg = tanh_fast(g2), og = sigm(g3);
                c1[e] = fg * c1[e] + ig * gg;
                h1v[e] = og * tanh_fast(c1[e]);
                hs[0][e][tid] = h1v[e];
            }
            wg_barrier();  // RAW
        }

        unsigned int* fbb = flagb + pr * NC;
        for (int c = 0; c < NC; ++c) {
            if (c > 0 && tid == 0)
                __hip_atomic_store(&fbb[c - 1], 1u,
                                   __ATOMIC_RELEASE, __HIP_MEMORY_SCOPE_AGENT);
            // prefetch next chunk's P records (used at j==7 and rotated after)
            int cnx = (c + 1 < NC) ? c + 1 : NC - 1;
            float4 Bq[NE][4];
#pragma unroll
            for (int e = 0; e < NE; ++e) {
                int eb = pr * NE + e;
                const float4* rp = (const float4*)(PT + (((size_t)eb * NC + cnx) * 8 + wv) * 16);
#pragma unroll
                for (int k = 0; k < 4; ++k) Bq[e][k] = rp[k];
            }
            float* mrec = mvalT + ((size_t)(pr * NC + c) * 8 + wv) * 32;

#pragma unroll
            for (int j = 0; j < 8; ++j) {
                int t = c * 8 + j;
                const int p = t & 1;
                float m1[NE], m2[NE], m3[NE], m4[NE];
#pragma unroll
                for (int e = 0; e < NE; ++e) {
                    float4 x0 = *(const float4*)&hs[p][e][4 * l];
                    float4 x1 = *(const float4*)&hs[p][e][256 + 4 * l];
                    float r1 = dot8(w22a, w22b, x0, x1);
                    float r2 = dot8(dw22a, dw22b, x0, x1);
                    float r3 = dot8(u12a, u12b, x0, x1);
                    float r4 = dot8(du12a, du12b, x0, x1);
                    m1[e] = bcast63(dpp_sum64(r1));
                    m2[e] = bcast63(dpp_sum64(r2));
                    m3[e] = bcast63(dpp_sum64(r3));
                    m4[e] = bcast63(dpp_sum64(r4));
                }
                if (l == 63) {
#pragma unroll
                    for (int e = 0; e < NE; ++e)
                        *(float2*)&mrec[e * 16 + j * 2] = make_float2(m1[e], m2[e]);
                }
                if (t < NS - 1) {
#pragma unroll
                    for (int e = 0; e < NE; ++e) {
                        float px = (j < 7) ? pa1[e][j + 1] : Bq[e][0].x;
                        float py = (j < 7) ? pa2[e][j + 1] : Bq[e][0].y;
                        float g0 = cW1[0] * px + cdW1[0] * py + cU1[0] * m3[e] + cdU1[0] * m4[e] + bb1[0];
                        float g1 = cW1[1] * px + cdW1[1] * py + cU1[1] * m3[e] + cdU1[1] * m4[e] + bb1[1];
                        float g2 = cW1[2] * px + cdW1[2] * py + cU1[2] * m3[e] + cdU1[2] * m4[e] + bb1[2];
                        float g3 = cW1[3] * px + cdW1[3] * py + cU1[3] * m3[e] + cdU1[3] * m4[e] + bb1[3];
                        float ig = sigm(g0), fg = sigm(g1), gg = tanh_fast(g2), og = sigm(g3);
                        c1[e] = fg * c1[e] + ig * gg;
                        h1v[e] = og * tanh_fast(c1[e]);
                        hs[p ^ 1][e][tid] = h1v[e];
                    }
                }
                if (j == 7) full_barrier(); else wg_barrier();
            }
            // rotate Bq -> pa
#pragma unroll
            for (int e = 0; e < NE; ++e)
#pragma unroll
                for (int k = 0; k < 4; ++k) {
                    float4 v = Bq[e][k];
                    pa1[e][2 * k] = v.x;     pa2[e][2 * k] = v.y;
                    pa1[e][2 * k + 1] = v.z; pa2[e][2 * k + 1] = v.w;
                }
        }
        if (tid == 0)
            __hip_atomic_store(&fbb[NC - 1], 1u,
                               __ATOMIC_RELEASE, __HIP_MEMORY_SCOPE_AGENT);
#pragma unroll
        for (int e = 0; e < NE; ++e) {
            int eb = pr * NE + e;
            hn[(size_t)eb * NH + h] = h1v[e];
            cn[(size_t)eb * NH + h] = c1[e];
        }
    } else {
        // =================== CONSUMER: layer 2 (x NE) ===================
        float4 u22a, u22b, du22a, du22b;
        LOADWP(U22, u22a, u22b)
        LOADWP(dU22, du22a, du22b)
        float cW2[4], cdW2[4], cU2[4], cdU2[4], bb2[4];
#pragma unroll
        for (int q = 0; q < 4; ++q) {
            int idx = q * 64 + l;
            cW2[q] = W21[idx]; cdW2[q] = dW21[idx];
            cU2[q] = U21[idx]; cdU2[q] = dU21[idx];
            bb2[q] = b21[q * NH + h] + b22[q * NH + h];
        }
        float c2[NE], h2v[NE];
#pragma unroll
        for (int e = 0; e < NE; ++e) {
            int eb = pr * NE + e;
            c2[e] = c0[(size_t)NB * NH + (size_t)eb * NH + h];
            h2v[e] = h0[(size_t)NB * NH + (size_t)eb * NH + h];
            hs[0][e][tid] = h2v[e];
        }
        wg_barrier();

        const unsigned int* fbb = flagb + pr * NC;
        for (int c = 0; c < NC; ++c) {
            while (__hip_atomic_load(&fbb[c], __ATOMIC_ACQUIRE,
                                     __HIP_MEMORY_SCOPE_AGENT) == 0) {}
            const float4* rm = (const float4*)(mvalT + ((size_t)(pr * NC + c) * 8 + wv) * 32);
            float q1a[NE][8], q2a[NE][8];
#pragma unroll
            for (int e = 0; e < NE; ++e)
#pragma unroll
                for (int k = 0; k < 4; ++k) {
                    float4 v = rm[e * 4 + k];
                    q1a[e][2 * k] = v.x;     q2a[e][2 * k] = v.y;
                    q1a[e][2 * k + 1] = v.z; q2a[e][2 * k + 1] = v.w;
                }

#pragma unroll
            for (int j = 0; j < 8; ++j) {
                int t = c * 8 + j;
                const int p = t & 1;
#pragma unroll
                for (int e = 0; e < NE; ++e) {
                    int eb = pr * NE + e;
                    float4 y0 = *(const float4*)&hs[p][e][4 * l];
                    float4 y1 = *(const float4*)&hs[p][e][256 + 4 * l];
                    float r5 = dot8(u22a, u22b, y0, y1);
                    float r6 = dot8(du22a, du22b, y0, y1);
                    float m5 = bcast63(dpp_sum64(r5));
                    float m6 = bcast63(dpp_sum64(r6));
                    float mx = q1a[e][j], my = q2a[e][j];
                    float g0 = cW2[0] * mx + cdW2[0] * my + cU2[0] * m5 + cdU2[0] * m6 + bb2[0];
                    float g1 = cW2[1] * mx + cdW2[1] * my + cU2[1] * m5 + cdU2[1] * m6 + bb2[1];
                    float g2 = cW2[2] * mx + cdW2[2] * my + cU2[2] * m5 + cdU2[2] * m6 + bb2[2];
                    float g3 = cW2[3] * mx + cdW2[3] * my + cU2[3] * m5 + cdU2[3] * m6 + bb2[3];
                    float ig = sigm(g0), fg = sigm(g1), gg = tanh_fast(g2), og = sigm(g3);
                    c2[e] = fg * c2[e] + ig * gg;
                    h2v[e] = og * tanh_fast(c2[e]);
                    hs[p ^ 1][e][tid] = h2v[e];
                    // scattered fire-and-forget (never waited in-loop)
                    out[(size_t)eb * NS * NH + (size_t)t * NH + h] = h2v[e];
                }
                wg_barrier();
            }
        }
#pragma unroll
        for (int e = 0; e < NE; ++e) {
            int eb = pr * NE + e;
            hn[(size_t)NB * NH + (size_t)eb * NH + h] = h2v[e];
            cn[(size_t)NB * NH + (size_t)eb * NH + h] = c2[e];
        }
    }
}

extern "C" void kernel_launch(void* const* d_in, const int* in_sizes, int n_in,
                              void* d_out, int out_size, void* d_ws, size_t ws_size,
                              hipStream_t stream) {
    const float* x = (const float*)d_in[0];
    const float* h0 = (const float*)d_in[1];
    const float* c0 = (const float*)d_in[2];
    const float* W11 = (const float*)d_in[3];
    const float* W12 = (const float*)d_in[4];
    const float* U11 = (const float*)d_in[5];
    const float* U12 = (const float*)d_in[6];
    const float* dW11 = (const float*)d_in[7];
    const float* dW12 = (const float*)d_in[8];
    const float* dU11 = (const float*)d_in[9];
    const float* dU12 = (const float*)d_in[10];
    const float* b11 = (const float*)d_in[11];
    const float* b12 = (const float*)d_in[12];
    const float* W21 = (const float*)d_in[13];
    const float* W22 = (const float*)d_in[14];
    const float* U21 = (const float*)d_in[15];
    const float* U22 = (const float*)d_in[16];
    const float* dW21 = (const float*)d_in[17];
    const float* dW22 = (const float*)d_in[18];
    const float* dU21 = (const float*)d_in[19];
    const float* dU22 = (const float*)d_in[20];
    const float* b21 = (const float*)d_in[21];
    const float* b22 = (const float*)d_in[22];

    char* ws = (char*)d_ws;
    float* PT = (float*)ws;                                  // 2 MB
    float* mvalT = (float*)(ws + (size_t)NB * NS * 16 * 4);  // 2 MB
    unsigned int* flagb = (unsigned int*)(ws + 2 * (size_t)NB * NS * 16 * 4);  // 8 KB
    float* out = (float*)d_out;

    hipMemsetAsync(flagb, 0, (NB / NE) * NC * sizeof(unsigned int), stream);
    hipLaunchKernelGGL(precomp_kernel, dim3(NB * NS), dim3(64), 0, stream,
                       x, W12, dW12, PT);
    hipLaunchKernelGGL(lstm_pipe_kernel, dim3(2 * (NB / NE)), dim3(512), 0, stream,
                       PT, h0, c0,
                       W11, U11, dW11, dU11, U12, dU12, b11, b12,
                       W21, U21, dW21, dU21, W22, dW22, U22, dU22, b21, b22,
                       mvalT, flagb, out);
}